// Round 13
// baseline (143.432 us; speedup 1.0000x reference)
//
#include <hip/hip_runtime.h>
#include <hip/hip_bf16.h>

typedef __attribute__((ext_vector_type(4)))  float f32x4;
typedef __attribute__((ext_vector_type(16))) float f32x16;
typedef __attribute__((ext_vector_type(8)))  short bf16x8;
typedef __attribute__((ext_vector_type(4)))  unsigned int u32x4;

__device__ __forceinline__ short f2bf(float x){
    __hip_bfloat16 h = __float2bfloat16(x);
    return __builtin_bit_cast(short, h);
}
__device__ __forceinline__ float bf2f(short x){
    unsigned int u = ((unsigned int)(unsigned short)x) << 16;
    return __builtin_bit_cast(float, u);
}
__device__ __forceinline__ unsigned int pk2bf(float x, float y){
    union { __hip_bfloat162 h; unsigned int u; } cv;
    float2 f; f.x = x; f.y = y;
    cv.h = __float22bfloat162_rn(f);                 // v_cvt_pk_bf16_f32
    return cv.u;
}

// ---------------------------------------------------------------- pre: dense scores + sparse copy + AB GEMM
// blocks 0..255   : dense_sparse body (16 docs x 32 q each)
// blocks 256..511 : Bws(bf16)[16 doc rows] = doc @ W1b
// blocks 512..513 : Aq(f32)[16 q rows]     = query @ W1a + b1
__global__ __launch_bounds__(256)
void pre_kernel(const float* __restrict__ query, const float* __restrict__ doc,
                const float* __restrict__ sparse, const float* __restrict__ W1,
                const float* __restrict__ b1,
                float* __restrict__ out_dense, float* __restrict__ out_sparse,
                short* __restrict__ Bws, float* __restrict__ Aq){
    __shared__ float ldsq[32*388];
    __shared__ float ldsd[16*388];
    const int b = blockIdx.x, tid = threadIdx.x;

    if (b < 256){
        const int d0 = b*16;
        #pragma unroll
        for (int i=0;i<12;i++){ int idx = tid + i*256; int row = idx/96, c4 = idx%96;
            *(f32x4*)(ldsq + row*388 + c4*4) = *(const f32x4*)(query + row*384 + c4*4); }
        #pragma unroll
        for (int i=0;i<6;i++){ int idx = tid + i*256; int row = idx/96, c4 = idx%96;
            *(f32x4*)(ldsd + row*388 + c4*4) = *(const f32x4*)(doc + (d0+row)*384 + c4*4); }
        __syncthreads();
        const int q = tid>>3, dg = tid&7;
        float acc0 = 0.0f, acc1 = 0.0f;
        #pragma unroll 4
        for (int k=0;k<384;k++){
            float qv = ldsq[q*388 + k];
            acc0 += qv*ldsd[dg*388 + k];
            acc1 += qv*ldsd[(dg+8)*388 + k];
        }
        out_dense[q*4096 + d0 + dg]     = acc0;
        out_dense[q*4096 + d0 + dg + 8] = acc1;
        if (tid < 128){
            int qq = tid>>2, c4 = tid&3;
            *(f32x4*)(out_sparse + qq*4096 + d0 + c4*4) = *(const f32x4*)(sparse + qq*4096 + d0 + c4*4);
        }
    } else {
        const int bb = b - 256;
        const int w = tid >> 6, lane = tid & 63;
        const int cl = lane & 15, quad = lane >> 4;
        const float* src; const float* wrow; int r0; bool isA;
        if (bb < 256){ r0 = bb*16;       src = doc;   wrow = W1 + 384*384; isA = false; }
        else         { r0 = (bb-256)*16; src = query; wrow = W1;           isA = true;  }

        f32x4 acc[6];
        #pragma unroll
        for (int t=0;t<6;t++) acc[t] = (f32x4){0.f,0.f,0.f,0.f};

        #pragma unroll 1
        for (int s=0;s<12;s++){
            const float* ap = src + (r0+cl)*384 + s*32 + quad*8;
            const f32x4 a0 = *(const f32x4*)ap;
            const f32x4 a1 = *(const f32x4*)(ap+4);
            u32x4 afu;
            afu[0] = pk2bf(a0[0], a0[1]); afu[1] = pk2bf(a0[2], a0[3]);
            afu[2] = pk2bf(a1[0], a1[1]); afu[3] = pk2bf(a1[2], a1[3]);
            const bf16x8 af = __builtin_bit_cast(bf16x8, afu);
            const float* wk = wrow + (s*32 + quad*8)*384;
            #pragma unroll
            for (int tt=0;tt<6;tt++){
                const int col = (w*6+tt)*16 + cl;
                u32x4 bu;
                #pragma unroll
                for (int p=0;p<4;p++)
                    bu[p] = pk2bf(wk[(2*p)*384 + col], wk[(2*p+1)*384 + col]);
                const bf16x8 bf_ = __builtin_bit_cast(bf16x8, bu);
                acc[tt] = __builtin_amdgcn_mfma_f32_16x16x32_bf16(af, bf_, acc[tt], 0, 0, 0);
            }
        }
        #pragma unroll
        for (int tt=0;tt<6;tt++){
            const int col = (w*6+tt)*16 + cl;
            if (isA){
                const float b1v = b1[col];
                #pragma unroll
                for (int r=0;r<4;r++)
                    Aq[(r0 + quad*4 + r)*384 + col] = acc[tt][r] + b1v;
            } else {
                #pragma unroll
                for (int r=0;r<4;r++)
                    Bws[(r0 + quad*4 + r)*384 + col] = f2bf(acc[tt][r]);
            }
        }
    }
}

// ---------------------------------------------------------------- main fused MLP kernel
// 256 blocks x 512 thr = 8 waves, 1 block/CU. One wave = one doc column x 32 q x 192 N via
// mfma_f32_32x32x16_bf16 (6 n-tiles). acc 96 AGPR + ~120 arch VGPR = ~215 of the 256-reg
// budget at 2 waves/SIMD. fr built once chip-wide via packed v_cvt_pk_bf16_f32; wc/wd read
// as f32 from W1 (L1-hot, no unpack); 1-deep prefetch of BOTH globals (bw/a) and LDS (bfr).
// A-frag: m=lane&31, k=(lane>>5)*8+j.  B-frag: n=lane&31, same k.
// C/D: col=lane&31, row=(reg&3)+8*(reg>>2)+4*(lane>>5)  [m74/m101-verified].
__global__ __launch_bounds__(512, 2)
void main_kernel(const float* __restrict__ Aq, const short* __restrict__ Bws,
                 const float* __restrict__ W1,
                 const float* __restrict__ b2, const float* __restrict__ W3,
                 const float* __restrict__ b3, const float* __restrict__ sparse,
                 const float* __restrict__ W2, const float* __restrict__ dense_in,
                 float* __restrict__ out_final){
    __shared__ short lw[73728];                      // 147,456 B
    const int tid = threadIdx.x;
    // stage W2 -> LDS in 32x32-tile order: chunk c=(s*6+t2)*64+lane_c, reg j = W2[k][n],
    // n = t2*32+(lane_c&31), k = s*16+((lane_c>>5)&1)*8+j
    #pragma unroll
    for (int i=0;i<18;i++){
        int c = tid + i*512;
        int lane_c = c & 63, st = c >> 6;
        int s = st/6, t2 = st%6;
        int n = t2*32 + (lane_c&31), kb = s*16 + ((lane_c>>5)&1)*8;
        u32x4 vu;
        #pragma unroll
        for (int p=0;p<4;p++)
            vu[p] = pk2bf(W2[(kb+2*p)*192 + n], W2[(kb+2*p+1)*192 + n]);
        *(bf16x8*)(lw + c*8) = __builtin_bit_cast(bf16x8, vu);
    }
    __syncthreads();                                 // only barrier in the kernel

    const int lane = tid & 63, w = tid >> 6;
    const int m = lane & 31, q2 = lane >> 5;
    const int kbase = q2*8;
    const float b3v = b3[0];
    const float* w1c = W1 + 768*384;
    const float* w1d = W1 + 769*384;

    #pragma unroll 1
    for (int t4=0; t4<2; t4++){
        const int dcol = blockIdx.x*16 + t4*8 + w;   // doc column, < 4096
        const float dsv = dense_in[m*4096 + dcol];
        const float ssv = sparse[m*4096 + dcol];

        f32x16 acc[6];
        #pragma unroll
        for (int t=0;t<6;t++)
            #pragma unroll
            for (int r=0;r<16;r++) acc[t][r] = 0.0f;

        // prefetch s=0: globals + LDS
        bf16x8 bw_c = *(const bf16x8*)(Bws + dcol*384 + kbase);
        f32x4  a0_c = *(const f32x4*)(Aq + m*384 + kbase);
        f32x4  a1_c = *(const f32x4*)(Aq + m*384 + kbase + 4);
        bf16x8 bfr_c[6];
        #pragma unroll
        for (int t=0;t<6;t++) bfr_c[t] = *(const bf16x8*)(lw + (t*64 + lane)*8);

        #pragma unroll 1
        for (int s=0;s<24;s++){
            const int k0 = s*16 + kbase;
            const int kn = (s < 23) ? (k0 + 16) : kbase;     // dummy wrap on last iter
            const int sn = (s < 23) ? (s + 1) : 0;
            const bf16x8 bw_n = *(const bf16x8*)(Bws + dcol*384 + kn);
            const f32x4  a0_n = *(const f32x4*)(Aq + m*384 + kn);
            const f32x4  a1_n = *(const f32x4*)(Aq + m*384 + kn + 4);
            bf16x8 bfr_n[6];
            #pragma unroll
            for (int t=0;t<6;t++) bfr_n[t] = *(const bf16x8*)(lw + ((sn*6 + t)*64 + lane)*8);

            const f32x4 wc0 = *(const f32x4*)(w1c + k0);
            const f32x4 wc1 = *(const f32x4*)(w1c + k0 + 4);
            const f32x4 wd0 = *(const f32x4*)(w1d + k0);
            const f32x4 wd1 = *(const f32x4*)(w1d + k0 + 4);
            float hv[8];
            #pragma unroll
            for (int j=0;j<4;j++){
                hv[j]   = fmaxf(a0_c[j] + bf2f(bw_c[j])   + dsv*wc0[j] + ssv*wd0[j], 0.0f);
                hv[4+j] = fmaxf(a1_c[j] + bf2f(bw_c[4+j]) + dsv*wc1[j] + ssv*wd1[j], 0.0f);
            }
            u32x4 fru;
            fru[0] = pk2bf(hv[0], hv[1]); fru[1] = pk2bf(hv[2], hv[3]);
            fru[2] = pk2bf(hv[4], hv[5]); fru[3] = pk2bf(hv[6], hv[7]);
            const bf16x8 fr = __builtin_bit_cast(bf16x8, fru);

            #pragma unroll
            for (int t=0;t<6;t++)
                acc[t] = __builtin_amdgcn_mfma_f32_32x32x16_bf16(fr, bfr_c[t], acc[t], 0, 0, 0);

            bw_c = bw_n; a0_c = a0_n; a1_c = a1_n;
            #pragma unroll
            for (int t=0;t<6;t++) bfr_c[t] = bfr_n[t];
        }

        // layer 3: p[r] = sum_n relu(h2[row_r][n]+b2[n])*W3[n]; this lane covers n = t*32+m
        float p[16];
        #pragma unroll
        for (int r=0;r<16;r++) p[r] = 0.0f;
        #pragma unroll
        for (int t=0;t<6;t++){
            const int n = t*32 + m;
            const float b2v = b2[n];
            const float w3v = W3[n];
            #pragma unroll
            for (int r=0;r<16;r++)
                p[r] += fmaxf(acc[t][r] + b2v, 0.0f) * w3v;
        }
        #pragma unroll
        for (int mask=1; mask<32; mask<<=1){
            #pragma unroll
            for (int r=0;r<16;r++) p[r] += __shfl_xor(p[r], mask);
        }
        float myp = p[0];
        #pragma unroll
        for (int r=1;r<16;r++) myp = (m==r) ? p[r] : myp;
        if (m < 16){
            const int row = (m&3) + 8*(m>>2) + 4*q2;
            float logit = myp + b3v;
            float wgt = 1.0f/(1.0f + __expf(-logit));
            float dd = dense_in[row*4096 + dcol];
            float ss = sparse[row*4096 + dcol];
            out_final[row*4096 + dcol] = wgt*dd + (1.0f - wgt)*ss;
        }
    }
}

// ---------------------------------------------------------------- launch
extern "C" void kernel_launch(void* const* d_in, const int* in_sizes, int n_in,
                              void* d_out, int out_size, void* d_ws, size_t ws_size,
                              hipStream_t stream){
    const float* query  = (const float*)d_in[0];
    const float* doc    = (const float*)d_in[1];
    const float* sparse = (const float*)d_in[2];
    const float* W1     = (const float*)d_in[3];
    const float* b1     = (const float*)d_in[4];
    const float* W2     = (const float*)d_in[5];
    const float* b2     = (const float*)d_in[6];
    const float* W3     = (const float*)d_in[7];
    const float* b3     = (const float*)d_in[8];

    float* out_final  = (float*)d_out;                 // [32,4096]
    float* out_dense  = (float*)d_out + 131072;        // [32,4096]
    float* out_sparse = (float*)d_out + 262144;        // [32,4096]

    // workspace layout (16B-aligned), total 3,194,880 B
    short* Bws = (short*)d_ws;                                    // 3,145,728 B  (bf16 [4096][384])
    float* Aq  = (float*)((char*)d_ws + 3145728);                 //    49,152 B  (f32  [32][384])

    hipLaunchKernelGGL(pre_kernel,  dim3(514), dim3(256), 0, stream,
                       query, doc, sparse, W1, b1, out_dense, out_sparse, Bws, Aq);
    hipLaunchKernelGGL(main_kernel, dim3(256), dim3(512), 0, stream,
                       Aq, Bws, W1, b2, W3, b3, sparse, W2, out_dense, out_final);
}